// Round 1
// baseline (666.950 us; speedup 1.0000x reference)
//
#include <hip/hip_runtime.h>
#include <cstddef>

// Problem constants (match reference; N/E derived from in_sizes at launch)
#define NF 256   // input features
#define NH 16    // hidden
#define NC 16    // classes

// ---------------------------------------------------------------------------
// K1: h = x @ W1   [N,256] x [256,16] -> [N,16]
// Block: 256 threads, 64 nodes/block. Thread owns 4 nodes x 1 column.
// W1 (16KB) staged fully in LDS; x staged in 64x64 k-chunks (16.6KB padded).
// LDS bank notes: xs row stride 65 -> node-group reads hit banks {b,b+4,b+8,b+12}
// (no conflict); w1s reads are 16-consecutive-bank broadcasts.
// ---------------------------------------------------------------------------
#define GEMM_NODES 64
#define KCHUNK 64

__global__ __launch_bounds__(256) void gemm1_kernel(
    const float* __restrict__ x, const float* __restrict__ W1,
    float* __restrict__ h, int N)
{
    __shared__ float w1s[NF * NH];                 // 16 KB
    __shared__ float xs[GEMM_NODES][KCHUNK + 1];   // 16.6 KB

    const int tid = threadIdx.x;

    // stage W1 (4096 floats) via float4
    {
        const float4* w4 = (const float4*)W1;
        float4* s4 = (float4*)w1s;
        #pragma unroll
        for (int i = tid; i < NF * NH / 4; i += 256) s4[i] = w4[i];
    }

    const int n0 = blockIdx.x * GEMM_NODES;
    const int j  = tid & 15;        // output column
    const int ng = tid >> 4;        // node group 0..15 -> nodes ng*4..ng*4+3

    float acc0 = 0.f, acc1 = 0.f, acc2 = 0.f, acc3 = 0.f;

    for (int kc = 0; kc < NF; kc += KCHUNK) {
        __syncthreads();
        // stage x tile: 64 nodes x 64 feats = 1024 float4, 4 per thread
        for (int i = tid; i < GEMM_NODES * (KCHUNK / 4); i += 256) {
            const int row = i >> 4;        // 16 float4 per row
            const int c4  = i & 15;
            const int n   = n0 + row;
            float4 v = make_float4(0.f, 0.f, 0.f, 0.f);
            if (n < N) v = ((const float4*)(x + (size_t)n * NF + kc))[c4];
            xs[row][c4 * 4 + 0] = v.x;
            xs[row][c4 * 4 + 1] = v.y;
            xs[row][c4 * 4 + 2] = v.z;
            xs[row][c4 * 4 + 3] = v.w;
        }
        __syncthreads();

        #pragma unroll
        for (int k = 0; k < KCHUNK; ++k) {
            const float w = w1s[(kc + k) * NH + j];
            acc0 += xs[ng * 4 + 0][k] * w;
            acc1 += xs[ng * 4 + 1][k] * w;
            acc2 += xs[ng * 4 + 2][k] * w;
            acc3 += xs[ng * 4 + 3][k] * w;
        }
    }

    const int nb = n0 + ng * 4;
    if (nb + 0 < N) h[(size_t)(nb + 0) * NH + j] = acc0;
    if (nb + 1 < N) h[(size_t)(nb + 1) * NH + j] = acc1;
    if (nb + 2 < N) h[(size_t)(nb + 2) * NH + j] = acc2;
    if (nb + 3 < N) h[(size_t)(nb + 3) * NH + j] = acc3;
}

// ---------------------------------------------------------------------------
// K2: in-degree count (no self loops): cnt[dst[e]] += 1
// ---------------------------------------------------------------------------
__global__ __launch_bounds__(256) void deg_kernel(
    const int* __restrict__ dst, int* __restrict__ cnt, int E)
{
    const int e = blockIdx.x * 256 + threadIdx.x;
    if (e < E) atomicAdd(&cnt[dst[e]], 1);
}

// ---------------------------------------------------------------------------
// K3: dinv[n] = rsqrt(cnt[n]+1);  h1[n][j] = b1[j] + h[n][j]*dinv[n]^2
// (folds GCN self-loop message and bias; fully overwrites h1 -> no memset)
// ---------------------------------------------------------------------------
__global__ __launch_bounds__(256) void init_kernel(
    const float* __restrict__ h, const int* __restrict__ cnt,
    const float* __restrict__ b1, float* __restrict__ h1,
    float* __restrict__ dinv, int N)
{
    const int idx = blockIdx.x * 256 + threadIdx.x;
    if (idx >= N * NH) return;
    const int n = idx >> 4;
    const int j = idx & 15;
    const float d = rsqrtf((float)(cnt[n] + 1));  // deg incl. self-loop, >= 1
    if (j == 0) dinv[n] = d;
    h1[idx] = b1[j] + h[idx] * d * d;
}

// ---------------------------------------------------------------------------
// K4: GCN edge aggregation: h1[dst] += h[src] * dinv[src]*dinv[dst]
// 16 lanes per edge (lane = feature). Gathers are 64B contiguous per edge.
// ---------------------------------------------------------------------------
__global__ __launch_bounds__(256) void gcn_edge_kernel(
    const int* __restrict__ src, const int* __restrict__ dst,
    const float* __restrict__ h, const float* __restrict__ dinv,
    float* __restrict__ h1, int E)
{
    const long long t = (long long)blockIdx.x * 256 + threadIdx.x;
    const long long e = t >> 4;
    if (e >= E) return;
    const int j = (int)(t & 15);
    const int s = src[e];
    const int d = dst[e];
    const float w = dinv[s] * dinv[d];
    atomicAdd(&h1[(size_t)d * NH + j], h[(size_t)s * NH + j] * w);
}

// ---------------------------------------------------------------------------
// K5: SAGE sum aggregation: agg[dst] += h1[src]
// ---------------------------------------------------------------------------
__global__ __launch_bounds__(256) void sage_edge_kernel(
    const int* __restrict__ src, const int* __restrict__ dst,
    const float* __restrict__ h1, float* __restrict__ agg, int E)
{
    const long long t = (long long)blockIdx.x * 256 + threadIdx.x;
    const long long e = t >> 4;
    if (e >= E) return;
    const int j = (int)(t & 15);
    const int s = src[e];
    const int d = dst[e];
    atomicAdd(&agg[(size_t)d * NH + j], h1[(size_t)s * NH + j]);
}

// ---------------------------------------------------------------------------
// K6: out = (agg/max(cnt,1)) @ Wl + h1 @ Wr + b2; log_softmax over 16 classes.
// 16 lanes per node; shuffle reductions within 16-lane groups.
// ---------------------------------------------------------------------------
__global__ __launch_bounds__(256) void out_kernel(
    const float* __restrict__ h1, const float* __restrict__ agg,
    const int* __restrict__ cnt,
    const float* __restrict__ Wl, const float* __restrict__ Wr,
    const float* __restrict__ b2, float* __restrict__ out, int N)
{
    __shared__ float wls[NH * NC];
    __shared__ float wrs[NH * NC];
    __shared__ float b2s[NC];
    const int tid = threadIdx.x;
    if (tid < NH * NC) { wls[tid] = Wl[tid]; wrs[tid] = Wr[tid]; }
    if (tid < NC) b2s[tid] = b2[tid];
    __syncthreads();

    const int idx = blockIdx.x * 256 + tid;
    const int n = idx >> 4;
    const int j = idx & 15;
    if (n >= N) return;

    const float rc = 1.0f / fmaxf((float)cnt[n], 1.0f);
    float o = b2s[j];
    #pragma unroll
    for (int k = 0; k < NH; ++k) {
        const float a = agg[(size_t)n * NH + k] * rc;   // broadcast within group
        const float hh = h1[(size_t)n * NH + k];
        o += a * wls[k * NC + j] + hh * wrs[k * NC + j];
    }

    // log_softmax across the 16 lanes of this node
    float m = o;
    #pragma unroll
    for (int off = 1; off < 16; off <<= 1)
        m = fmaxf(m, __shfl_xor(m, off, 16));
    const float ex = expf(o - m);
    float ssum = ex;
    #pragma unroll
    for (int off = 1; off < 16; off <<= 1)
        ssum += __shfl_xor(ssum, off, 16);

    out[idx] = (o - m) - logf(ssum);
}

// ---------------------------------------------------------------------------
extern "C" void kernel_launch(void* const* d_in, const int* in_sizes, int n_in,
                              void* d_out, int out_size, void* d_ws, size_t ws_size,
                              hipStream_t stream)
{
    const float* x  = (const float*)d_in[0];
    const int*   ei = (const int*)d_in[1];
    const float* W1 = (const float*)d_in[2];
    const float* b1 = (const float*)d_in[3];
    const float* Wl = (const float*)d_in[4];
    const float* Wr = (const float*)d_in[5];
    const float* b2 = (const float*)d_in[6];
    float* out = (float*)d_out;

    const int N = in_sizes[0] / NF;
    const int E = in_sizes[1] / 2;
    const int* src = ei;       // edge_index[0]
    const int* dst = ei + E;   // edge_index[1]

    // workspace layout (floats): h[16N] | h1[16N] | agg[16N] | dinv[N] | cnt[N]
    float* h    = (float*)d_ws;
    float* h1   = h   + (size_t)N * NH;
    float* agg  = h1  + (size_t)N * NH;
    float* dinv = agg + (size_t)N * NH;
    int*   cnt  = (int*)(dinv + N);

    hipMemsetAsync(cnt, 0, (size_t)N * sizeof(int), stream);
    hipMemsetAsync(agg, 0, (size_t)N * NH * sizeof(float), stream);

    deg_kernel<<<(E + 255) / 256, 256, 0, stream>>>(dst, cnt, E);
    gemm1_kernel<<<(N + GEMM_NODES - 1) / GEMM_NODES, 256, 0, stream>>>(x, W1, h, N);
    init_kernel<<<(N * NH + 255) / 256, 256, 0, stream>>>(h, cnt, b1, h1, dinv, N);

    const long long edge_threads = (long long)E * 16;
    const int edge_blocks = (int)((edge_threads + 255) / 256);
    gcn_edge_kernel<<<edge_blocks, 256, 0, stream>>>(src, dst, h, dinv, h1, E);
    sage_edge_kernel<<<edge_blocks, 256, 0, stream>>>(src, dst, h1, agg, E);

    out_kernel<<<(N * NH + 255) / 256, 256, 0, stream>>>(h1, agg, cnt, Wl, Wr, b2, out, N);
}

// Round 2
// 568.842 us; speedup vs baseline: 1.1725x; 1.1725x over previous
//
#include <hip/hip_runtime.h>
#include <cstddef>

// Problem constants
#define NF 256   // input features
#define NH 16    // hidden
#define NC 16    // classes

#define SCAN_CHUNK 1024  // cnt elements per scan block (256 thr x 4)

// ---------------------------------------------------------------------------
// K1: h = x @ W1   [N,256] x [256,16] -> [N,16]   (unchanged from R1)
// ---------------------------------------------------------------------------
#define GEMM_NODES 64
#define KCHUNK 64

__global__ __launch_bounds__(256) void gemm1_kernel(
    const float* __restrict__ x, const float* __restrict__ W1,
    float* __restrict__ h, int N)
{
    __shared__ float w1s[NF * NH];                 // 16 KB
    __shared__ float xs[GEMM_NODES][KCHUNK + 1];   // 16.6 KB

    const int tid = threadIdx.x;
    {
        const float4* w4 = (const float4*)W1;
        float4* s4 = (float4*)w1s;
        #pragma unroll
        for (int i = tid; i < NF * NH / 4; i += 256) s4[i] = w4[i];
    }

    const int n0 = blockIdx.x * GEMM_NODES;
    const int j  = tid & 15;
    const int ng = tid >> 4;

    float acc0 = 0.f, acc1 = 0.f, acc2 = 0.f, acc3 = 0.f;

    for (int kc = 0; kc < NF; kc += KCHUNK) {
        __syncthreads();
        for (int i = tid; i < GEMM_NODES * (KCHUNK / 4); i += 256) {
            const int row = i >> 4;
            const int c4  = i & 15;
            const int n   = n0 + row;
            float4 v = make_float4(0.f, 0.f, 0.f, 0.f);
            if (n < N) v = ((const float4*)(x + (size_t)n * NF + kc))[c4];
            xs[row][c4 * 4 + 0] = v.x;
            xs[row][c4 * 4 + 1] = v.y;
            xs[row][c4 * 4 + 2] = v.z;
            xs[row][c4 * 4 + 3] = v.w;
        }
        __syncthreads();

        #pragma unroll
        for (int k = 0; k < KCHUNK; ++k) {
            const float w = w1s[(kc + k) * NH + j];
            acc0 += xs[ng * 4 + 0][k] * w;
            acc1 += xs[ng * 4 + 1][k] * w;
            acc2 += xs[ng * 4 + 2][k] * w;
            acc3 += xs[ng * 4 + 3][k] * w;
        }
    }

    const int nb = n0 + ng * 4;
    if (nb + 0 < N) h[(size_t)(nb + 0) * NH + j] = acc0;
    if (nb + 1 < N) h[(size_t)(nb + 1) * NH + j] = acc1;
    if (nb + 2 < N) h[(size_t)(nb + 2) * NH + j] = acc2;
    if (nb + 3 < N) h[(size_t)(nb + 3) * NH + j] = acc3;
}

// ---------------------------------------------------------------------------
// K2: in-degree count: cnt[dst[e]] += 1
// ---------------------------------------------------------------------------
__global__ __launch_bounds__(256) void deg_kernel(
    const int* __restrict__ dst, int* __restrict__ cnt, int E)
{
    const int e = blockIdx.x * 256 + threadIdx.x;
    if (e < E) atomicAdd(&cnt[dst[e]], 1);
}

// ---------------------------------------------------------------------------
// Scan A: per-block sums of cnt (1024 elements/block)
// ---------------------------------------------------------------------------
__global__ __launch_bounds__(256) void scanA_kernel(
    const int* __restrict__ cnt, int* __restrict__ bsum, int N)
{
    const int t = threadIdx.x;
    const int base = blockIdx.x * SCAN_CHUNK + t * 4;
    int s = 0;
    #pragma unroll
    for (int i = 0; i < 4; ++i) { int idx = base + i; if (idx < N) s += cnt[idx]; }
    #pragma unroll
    for (int off = 32; off; off >>= 1) s += __shfl_down(s, off, 64);
    __shared__ int ws[4];
    const int lane = t & 63, wv = t >> 6;
    if (lane == 0) ws[wv] = s;
    __syncthreads();
    if (t == 0) bsum[blockIdx.x] = ws[0] + ws[1] + ws[2] + ws[3];
}

// ---------------------------------------------------------------------------
// Scan B: single-block exclusive scan of block sums (nb <= 128)
// ---------------------------------------------------------------------------
__global__ __launch_bounds__(128) void scanB_kernel(int* __restrict__ bsum, int nb)
{
    __shared__ int tmp[128];
    const int t = threadIdx.x;
    int x = (t < nb) ? bsum[t] : 0;
    tmp[t] = x;
    __syncthreads();
    for (int off = 1; off < 128; off <<= 1) {
        int y = (t >= off) ? tmp[t - off] : 0;
        __syncthreads();
        tmp[t] += y;
        __syncthreads();
    }
    if (t < nb) bsum[t] = tmp[t] - x;   // exclusive
}

// ---------------------------------------------------------------------------
// Scan C: per-block exclusive scan of cnt + block offset -> rowptr
// ---------------------------------------------------------------------------
__global__ __launch_bounds__(256) void scanC_kernel(
    const int* __restrict__ cnt, const int* __restrict__ bscan,
    int* __restrict__ rowptr, int N)
{
    const int t = threadIdx.x;
    const int base = blockIdx.x * SCAN_CHUNK + t * 4;
    int v[4]; int s = 0;
    #pragma unroll
    for (int i = 0; i < 4; ++i) { int idx = base + i; v[i] = (idx < N) ? cnt[idx] : 0; s += v[i]; }
    const int lane = t & 63, wv = t >> 6;
    int inc = s;
    #pragma unroll
    for (int off = 1; off < 64; off <<= 1) {
        int y = __shfl_up(inc, off, 64);
        if (lane >= off) inc += y;
    }
    __shared__ int wsum[4];
    if (lane == 63) wsum[wv] = inc;
    __syncthreads();
    int woff = 0;
    for (int w = 0; w < wv; ++w) woff += wsum[w];
    int run = bscan[blockIdx.x] + woff + (inc - s);
    #pragma unroll
    for (int i = 0; i < 4; ++i) {
        int idx = base + i;
        if (idx < N) rowptr[idx] = run;
        run += v[i];
    }
}

// ---------------------------------------------------------------------------
// Scatter: build adjacency (incoming-edge src lists, grouped by dst)
// ---------------------------------------------------------------------------
__global__ __launch_bounds__(256) void scatter_kernel(
    const int* __restrict__ src, const int* __restrict__ dst,
    const int* __restrict__ rowptr, int* __restrict__ fill,
    int* __restrict__ csrc, int E)
{
    const int e = blockIdx.x * 256 + threadIdx.x;
    if (e >= E) return;
    const int d = dst[e];
    const int pos = rowptr[d] + atomicAdd(&fill[d], 1);
    csrc[pos] = src[e];
}

// ---------------------------------------------------------------------------
// Init: dinv[n] = rsqrt(cnt+1); hs = h * dinv[n]  (in place)
// ---------------------------------------------------------------------------
__global__ __launch_bounds__(256) void init_kernel(
    float* __restrict__ hs, const int* __restrict__ cnt,
    float* __restrict__ dinv, int N)
{
    const int idx = blockIdx.x * 256 + threadIdx.x;
    if (idx >= N * NH) return;
    const int n = idx >> 4;
    const float d = rsqrtf((float)(cnt[n] + 1));
    if ((idx & 15) == 0) dinv[n] = d;
    hs[idx] *= d;
}

// ---------------------------------------------------------------------------
// GCN gather: h1[n] = b1 + dinv[n] * (hs[n] + sum_{in-edges} hs[src])
// 16 lanes per node (lane = feature); 4-wide unrolled gather loop.
// ---------------------------------------------------------------------------
__global__ __launch_bounds__(256) void gcn_gather_kernel(
    const float* __restrict__ hs, const int* __restrict__ csrc,
    const int* __restrict__ rowptr, const int* __restrict__ cnt,
    const float* __restrict__ dinv, const float* __restrict__ b1,
    float* __restrict__ h1, int N)
{
    const int tid = threadIdx.x;
    const int n = blockIdx.x * 16 + (tid >> 4);
    if (n >= N) return;
    const int j = tid & 15;
    const int start = rowptr[n];
    const int end = start + cnt[n];
    float acc = hs[(size_t)n * NH + j];   // self-loop term
    int k = start;
    for (; k + 4 <= end; k += 4) {
        const int s0 = csrc[k], s1 = csrc[k+1], s2 = csrc[k+2], s3 = csrc[k+3];
        const float a0 = hs[(size_t)s0 * NH + j];
        const float a1 = hs[(size_t)s1 * NH + j];
        const float a2 = hs[(size_t)s2 * NH + j];
        const float a3 = hs[(size_t)s3 * NH + j];
        acc += (a0 + a1) + (a2 + a3);
    }
    for (; k < end; ++k) acc += hs[(size_t)csrc[k] * NH + j];
    h1[(size_t)n * NH + j] = b1[j] + dinv[n] * acc;
}

// ---------------------------------------------------------------------------
// SAGE gather fused with output GEMM + log_softmax.
// agg = mean_{in-edges} h1[src]; o = agg@Wl + h1@Wr + b2; log_softmax.
// ---------------------------------------------------------------------------
__global__ __launch_bounds__(256) void sage_out_kernel(
    const float* __restrict__ h1, const int* __restrict__ csrc,
    const int* __restrict__ rowptr, const int* __restrict__ cnt,
    const float* __restrict__ Wl, const float* __restrict__ Wr,
    const float* __restrict__ b2, float* __restrict__ out, int N)
{
    __shared__ float wls[NH * NC];
    __shared__ float wrs[NH * NC];
    __shared__ float b2s[NC];
    const int tid = threadIdx.x;
    if (tid < NH * NC) { wls[tid] = Wl[tid]; wrs[tid] = Wr[tid]; }
    if (tid < NC) b2s[tid] = b2[tid];
    __syncthreads();

    const int n = blockIdx.x * 16 + (tid >> 4);
    if (n >= N) return;
    const int j = tid & 15;
    const int start = rowptr[n];
    const int deg = cnt[n];
    const int end = start + deg;

    float acc = 0.f;
    int k = start;
    for (; k + 4 <= end; k += 4) {
        const int s0 = csrc[k], s1 = csrc[k+1], s2 = csrc[k+2], s3 = csrc[k+3];
        acc += (h1[(size_t)s0 * NH + j] + h1[(size_t)s1 * NH + j])
             + (h1[(size_t)s2 * NH + j] + h1[(size_t)s3 * NH + j]);
    }
    for (; k < end; ++k) acc += h1[(size_t)csrc[k] * NH + j];

    const float aggj = acc / fmaxf((float)deg, 1.0f);
    const float h1j  = h1[(size_t)n * NH + j];

    float o = b2s[j];
    #pragma unroll
    for (int kk = 0; kk < NH; ++kk) {
        const float a  = __shfl(aggj, kk, 16);
        const float hh = __shfl(h1j,  kk, 16);
        o += a * wls[kk * NC + j] + hh * wrs[kk * NC + j];
    }

    float m = o;
    #pragma unroll
    for (int off = 1; off < 16; off <<= 1) m = fmaxf(m, __shfl_xor(m, off, 16));
    const float ex = expf(o - m);
    float ssum = ex;
    #pragma unroll
    for (int off = 1; off < 16; off <<= 1) ssum += __shfl_xor(ssum, off, 16);

    out[(size_t)n * NC + j] = (o - m) - logf(ssum);
}

// ---------------------------------------------------------------------------
extern "C" void kernel_launch(void* const* d_in, const int* in_sizes, int n_in,
                              void* d_out, int out_size, void* d_ws, size_t ws_size,
                              hipStream_t stream)
{
    const float* x  = (const float*)d_in[0];
    const int*   ei = (const int*)d_in[1];
    const float* W1 = (const float*)d_in[2];
    const float* b1 = (const float*)d_in[3];
    const float* Wl = (const float*)d_in[4];
    const float* Wr = (const float*)d_in[5];
    const float* b2 = (const float*)d_in[6];
    float* out = (float*)d_out;

    const int N = in_sizes[0] / NF;
    const int E = in_sizes[1] / 2;
    const int* src = ei;       // edge_index[0]
    const int* dst = ei + E;   // edge_index[1]

    // workspace: h[16N] | h1[16N] | dinv[N] | cnt[N] | fill[N] | rowptr[N] | bsum[128] | csrc[E]
    float* h      = (float*)d_ws;
    float* h1     = h    + (size_t)N * NH;
    float* dinv   = h1   + (size_t)N * NH;
    int*   cnt    = (int*)(dinv + N);
    int*   fill   = cnt  + N;
    int*   rowptr = fill + N;
    int*   bsum   = rowptr + N;
    int*   csrc   = bsum + 128;

    const int nScanBlk = (N + SCAN_CHUNK - 1) / SCAN_CHUNK;   // 98 for N=100k

    // zero cnt+fill in one shot (adjacent)
    hipMemsetAsync(cnt, 0, (size_t)2 * N * sizeof(int), stream);

    deg_kernel<<<(E + 255) / 256, 256, 0, stream>>>(dst, cnt, E);
    scanA_kernel<<<nScanBlk, 256, 0, stream>>>(cnt, bsum, N);
    scanB_kernel<<<1, 128, 0, stream>>>(bsum, nScanBlk);
    scanC_kernel<<<nScanBlk, 256, 0, stream>>>(cnt, bsum, rowptr, N);
    scatter_kernel<<<(E + 255) / 256, 256, 0, stream>>>(src, dst, rowptr, fill, csrc, E);

    gemm1_kernel<<<(N + GEMM_NODES - 1) / GEMM_NODES, 256, 0, stream>>>(x, W1, h, N);
    init_kernel<<<(N * NH + 255) / 256, 256, 0, stream>>>(h, cnt, dinv, N);

    const int nodeBlk = (N + 15) / 16;
    gcn_gather_kernel<<<nodeBlk, 256, 0, stream>>>(h, csrc, rowptr, cnt, dinv, b1, h1, N);
    sage_out_kernel<<<nodeBlk, 256, 0, stream>>>(h1, csrc, rowptr, cnt, Wl, Wr, b2, out, N);
}